// Round 6
// baseline (371.567 us; speedup 1.0000x reference)
//
#include <hip/hip_runtime.h>

// Sparse conv, sorted-message pipeline v4.
//   memset count
//   prep (fused): xcvt x->bf16 | histogram out_map | W -> MFMA-fragment layout (Wf)
//   scan1/2/3:    exclusive prefix over count -> cursor (segment starts)
//   gemm:         distance-2 pipelined gather -> bf16 MFMA -> msg row at sorted slot
//                 (slot = atomicAdd(cursor[out]), 2 atomics/thread, shfl-distributed)
//   gather:       8 output rows per wave, contiguous segment sum, direct store.

typedef __attribute__((ext_vector_type(8))) short bf16x8;
typedef __attribute__((ext_vector_type(8))) unsigned short u16x8;
typedef __attribute__((ext_vector_type(4))) float f32x4;

constexpr int KOFF = 27;
constexpr int M = 65536;
constexpr int CIN = 64;
constexpr int COUT = 64;
constexpr int NVOX = 262144;
constexpr int NMSG = KOFF * M;                 // 1,769,472
constexpr int TM_BLOCK = 512;
constexpr int TILES_PER_K = M / TM_BLOCK;      // 128
constexpr int SUBTILES = TM_BLOCK / (4 * 16);  // 8
constexpr int XCVT_BLOCKS = NVOX * CIN / 8 / 256;  // 8192
constexpr int COUNT_BLOCKS = NMSG / 256;           // 6912

static __device__ __forceinline__ short f2bf(float f) {
  unsigned u = __builtin_bit_cast(unsigned, f);
  unsigned r = (u + 0x7FFFu + ((u >> 16) & 1u)) >> 16;
  return (short)r;
}
static __device__ __forceinline__ float bf2f(unsigned short h) {
  return __builtin_bit_cast(float, (unsigned)h << 16);
}

// ---------------- fused prep: xcvt | count | W-fragment ----------------

__global__ __launch_bounds__(256) void prep_kernel(
    const float* __restrict__ x, const float* __restrict__ W,
    const int* __restrict__ out_map, unsigned short* __restrict__ xb,
    unsigned short* __restrict__ Wf, int* __restrict__ count, int xcvtBlocks) {
  const int b = blockIdx.x;
  if (b < xcvtBlocks) {
    int i = b * 256 + threadIdx.x;
    const float4* p = (const float4*)x + (size_t)i * 2;
    float4 a = p[0], q = p[1];
    u16x8 h;
    h[0] = (unsigned short)f2bf(a.x); h[1] = (unsigned short)f2bf(a.y);
    h[2] = (unsigned short)f2bf(a.z); h[3] = (unsigned short)f2bf(a.w);
    h[4] = (unsigned short)f2bf(q.x); h[5] = (unsigned short)f2bf(q.y);
    h[6] = (unsigned short)f2bf(q.z); h[7] = (unsigned short)f2bf(q.w);
    *(u16x8*)(xb + (size_t)i * 8) = h;
  } else if (b < xcvtBlocks + COUNT_BLOCKS) {
    int i = (b - xcvtBlocks) * 256 + threadIdx.x;
    atomicAdd(&count[out_map[i]], 1);
  } else {
    // W[k] -> fragment order: Wf[k][(t*2+u)*64 + l][j] = W[k][u*32+(l>>4)*8+j][t*16+(l&15)]
    int k = b - xcvtBlocks - COUNT_BLOCKS;  // 0..26
    const float* Wk = W + (size_t)k * (CIN * COUT);
    unsigned short* dst = Wf + (size_t)k * 4096;
#pragma unroll
    for (int i = 0; i < 16; ++i) {
      int e = threadIdx.x * 16 + i;
      int j = e & 7, l = (e >> 3) & 63, tu = e >> 9;
      int t = tu >> 1, u = tu & 1;
      dst[e] = (unsigned short)f2bf(Wk[(u * 32 + (l >> 4) * 8 + j) * COUT + t * 16 + (l & 15)]);
    }
  }
}

// ---------------- scan ----------------

__global__ __launch_bounds__(256) void scan1_kernel(const int* __restrict__ count,
                                                    int* __restrict__ cursor,
                                                    int* __restrict__ blockSums) {
  __shared__ int s[256];
  int t = threadIdx.x, i = blockIdx.x * 256 + t;  // grid = 1024
  int c = count[i];
  s[t] = c; __syncthreads();
  for (int off = 1; off < 256; off <<= 1) {
    int add = (t >= off) ? s[t - off] : 0;
    __syncthreads(); s[t] += add; __syncthreads();
  }
  cursor[i] = s[t] - c;
  if (t == 255) blockSums[blockIdx.x] = s[t];
}

__global__ __launch_bounds__(256) void scan2_kernel(int* __restrict__ bs) {
  __shared__ int s[256];
  int t = threadIdx.x;
  int v0 = bs[t*4], v1 = bs[t*4+1], v2 = bs[t*4+2], v3 = bs[t*4+3];
  int sum = v0 + v1 + v2 + v3;
  s[t] = sum; __syncthreads();
  for (int off = 1; off < 256; off <<= 1) {
    int add = (t >= off) ? s[t - off] : 0;
    __syncthreads(); s[t] += add; __syncthreads();
  }
  int run = s[t] - sum;
  bs[t*4] = run; run += v0;
  bs[t*4+1] = run; run += v1;
  bs[t*4+2] = run; run += v2;
  bs[t*4+3] = run;
}

__global__ __launch_bounds__(256) void scan3_kernel(int* __restrict__ cursor,
                                                    const int* __restrict__ blockBase) {
  int i = blockIdx.x * 256 + threadIdx.x;  // grid = 1024
  cursor[i] += blockBase[blockIdx.x];
}

// ---------------- phase A: pipelined GEMM -> msg at sorted slots ----------------

template <bool BF16IN>
__global__ __launch_bounds__(256) void gemm_msg_kernel(
    const void* __restrict__ xin, const unsigned short* __restrict__ Wf,
    const int* __restrict__ in_map, const int* __restrict__ out_map,
    int* __restrict__ cursor, unsigned short* __restrict__ msg) {
  const int k = blockIdx.x / TILES_PER_K;
  const int mblock = (blockIdx.x % TILES_PER_K) * TM_BLOCK;
  const int wave = threadIdx.x >> 6;
  const int l = threadIdx.x & 63;
  const int lg = l >> 4;
  const int lr = l & 15;

  // B fragments: 8 coalesced 16B loads (vs 64 scalar W loads).
  bf16x8 bfrag[4][2];
  const bf16x8* wf = (const bf16x8*)(Wf + (size_t)k * 4096);
#pragma unroll
  for (int t = 0; t < 4; ++t)
#pragma unroll
    for (int u = 0; u < 2; ++u)
      bfrag[t][u] = wf[(t * 2 + u) * 64 + l];

  const int mwave = mblock + wave * (TM_BLOCK / 4);  // this wave's 128 rows
  const int rb = k * M + mwave;
  int slotA = atomicAdd(&cursor[out_map[rb + l]], 1);       // rows 0..63
  int slotB = atomicAdd(&cursor[out_map[rb + 64 + l]], 1);  // rows 64..127

  auto loadA = [&](int s, bf16x8& A0, bf16x8& A1) {
    int id = in_map[rb + s * 16 + lr];
    if (BF16IN) {
      const unsigned short* xr = (const unsigned short*)xin + (size_t)id * CIN + lg * 8;
      A0 = *(const bf16x8*)(xr);
      A1 = *(const bf16x8*)(xr + 32);
    } else {
      const float* xr = (const float*)xin + (size_t)id * CIN + lg * 8;
      float4 x0 = *(const float4*)(xr);
      float4 x1 = *(const float4*)(xr + 4);
      float4 x2 = *(const float4*)(xr + 32);
      float4 x3 = *(const float4*)(xr + 36);
      A0[0]=f2bf(x0.x); A0[1]=f2bf(x0.y); A0[2]=f2bf(x0.z); A0[3]=f2bf(x0.w);
      A0[4]=f2bf(x1.x); A0[5]=f2bf(x1.y); A0[6]=f2bf(x1.z); A0[7]=f2bf(x1.w);
      A1[0]=f2bf(x2.x); A1[1]=f2bf(x2.y); A1[2]=f2bf(x2.z); A1[3]=f2bf(x2.w);
      A1[4]=f2bf(x3.x); A1[5]=f2bf(x3.y); A1[6]=f2bf(x3.z); A1[7]=f2bf(x3.w);
    }
  };

  bf16x8 c0, c1, n0, n1;
  loadA(0, c0, c1);
  loadA(1, n0, n1);

#pragma unroll 1
  for (int s = 0; s < SUBTILES; ++s) {
    // Prefetch subtile s+2 (distance-2: two compute iterations hide gather latency).
    bf16x8 p0, p1;
    const bool have = (s + 2 < SUBTILES);
    if (have) loadA(s + 2, p0, p1);

    f32x4 acc[4] = {{0.f,0.f,0.f,0.f},{0.f,0.f,0.f,0.f},{0.f,0.f,0.f,0.f},{0.f,0.f,0.f,0.f}};
#pragma unroll
    for (int t = 0; t < 4; ++t) {
      acc[t] = __builtin_amdgcn_mfma_f32_16x16x32_bf16(c0, bfrag[t][0], acc[t], 0, 0, 0);
      acc[t] = __builtin_amdgcn_mfma_f32_16x16x32_bf16(c1, bfrag[t][1], acc[t], 0, 0, 0);
    }

    // Row layout: position p = lr*4 + t holds channel t*16 + lr.
    const int slotsrc = (s < 4) ? slotA : slotB;
#pragma unroll
    for (int r = 0; r < 4; ++r) {
      const int sl = __shfl(slotsrc, (s * 16 + lg * 4 + r) & 63, 64);
      ushort4 h;
      h.x = (unsigned short)f2bf(acc[0][r]);
      h.y = (unsigned short)f2bf(acc[1][r]);
      h.z = (unsigned short)f2bf(acc[2][r]);
      h.w = (unsigned short)f2bf(acc[3][r]);
      *(ushort4*)(msg + (size_t)sl * 64 + lr * 4) = h;
    }

    c0 = n0; c1 = n1;
    if (have) { n0 = p0; n1 = p1; }
  }
}

// ---------------- phase B: contiguous segment sum, 8 rows per wave ----------------

__global__ __launch_bounds__(256) void gather_out_kernel(
    const unsigned short* __restrict__ msg, const int* __restrict__ cursorEnd,
    const int* __restrict__ count, float* __restrict__ out) {
  const int wid = (blockIdx.x * 256 + threadIdx.x) >> 6;  // grid = NVOX/32 blocks
  const int p = threadIdx.x & 63;
  const int o0 = wid * 8;
  const int rsub = p >> 3;       // row-within-chunk 0..7
  const int qb = (p & 7) * 8;    // position base within row

  int n[8], base[8];
#pragma unroll
  for (int j = 0; j < 8; ++j) {
    n[j] = count[o0 + j];
    int e = cursorEnd[o0 + j];
    base[j] = (n[j] > 0) ? (e - n[j]) : 0;  // clamp empty segments (avoid OOB probe)
  }

  float acc[8][8] = {};
  // First chunk: 8 independent load chains (MLP depth 8).
#pragma unroll
  for (int j = 0; j < 8; ++j) {
    int safe = (rsub < n[j]) ? rsub : 0;
    u16x8 v = *(const u16x8*)(msg + (size_t)(base[j] + safe) * 64 + qb);
    if (rsub < n[j]) {
#pragma unroll
      for (int d = 0; d < 8; ++d) acc[j][d] += bf2f((unsigned short)v[d]);
    }
  }
  // Rare tail (n > 8); wave-uniform trip counts.
#pragma unroll
  for (int j = 0; j < 8; ++j) {
    for (int it = 1; it * 8 < n[j]; ++it) {
      int row = it * 8 + rsub;
      int safe = (row < n[j]) ? row : 0;
      u16x8 v = *(const u16x8*)(msg + (size_t)(base[j] + safe) * 64 + qb);
      if (row < n[j]) {
#pragma unroll
        for (int d = 0; d < 8; ++d) acc[j][d] += bf2f((unsigned short)v[d]);
      }
    }
  }

  // Sum across the 8 row-slots (lane bits 3..5).
#pragma unroll
  for (int j = 0; j < 8; ++j)
#pragma unroll
    for (int s = 8; s < 64; s <<= 1)
#pragma unroll
      for (int d = 0; d < 8; ++d) acc[j][d] += __shfl_xor(acc[j][d], s, 64);

  // position q=(p&7)*8+d -> channel (d&3)*16 + 2*(p&7) + (d>>2); lanes 0..7 write.
  if (p < 8) {
#pragma unroll
    for (int j = 0; j < 8; ++j) {
      float* orow = out + (size_t)(o0 + j) * 64 + 2 * p;
      *(float2*)(orow)      = make_float2(acc[j][0], acc[j][4]);
      *(float2*)(orow + 16) = make_float2(acc[j][1], acc[j][5]);
      *(float2*)(orow + 32) = make_float2(acc[j][2], acc[j][6]);
      *(float2*)(orow + 48) = make_float2(acc[j][3], acc[j][7]);
    }
  }
}

// ---------------- fallback (atomic scatter) ----------------

__global__ __launch_bounds__(256) void spconv_atomic_kernel(
    const float* __restrict__ x, const float* __restrict__ W,
    const int* __restrict__ in_map, const int* __restrict__ out_map,
    float* __restrict__ out) {
  const int k = blockIdx.x / TILES_PER_K;
  const int mblock = (blockIdx.x % TILES_PER_K) * TM_BLOCK;
  const int wave = threadIdx.x >> 6;
  const int l = threadIdx.x & 63;
  const int lg = l >> 4;
  const int lr = l & 15;
  bf16x8 bfrag[4][2];
  const float* Wk = W + (size_t)k * (CIN * COUT);
#pragma unroll
  for (int t = 0; t < 4; ++t)
#pragma unroll
    for (int u = 0; u < 2; ++u)
#pragma unroll
      for (int j = 0; j < 8; ++j)
        bfrag[t][u][j] = f2bf(Wk[(u * 32 + lg * 8 + j) * COUT + t * 16 + lr]);
  const int mwave = mblock + wave * (TM_BLOCK / 4);
#pragma unroll 1
  for (int s = 0; s < SUBTILES; ++s) {
    const int mbase = mwave + s * 16;
    const int in_idx = in_map[k * M + mbase + lr];
    const float* xr = x + (size_t)in_idx * CIN + lg * 8;
    float4 x0 = *(const float4*)(xr);
    float4 x1 = *(const float4*)(xr + 4);
    float4 x2 = *(const float4*)(xr + 32);
    float4 x3 = *(const float4*)(xr + 36);
    bf16x8 a0, a1;
    a0[0]=f2bf(x0.x); a0[1]=f2bf(x0.y); a0[2]=f2bf(x0.z); a0[3]=f2bf(x0.w);
    a0[4]=f2bf(x1.x); a0[5]=f2bf(x1.y); a0[6]=f2bf(x1.z); a0[7]=f2bf(x1.w);
    a1[0]=f2bf(x2.x); a1[1]=f2bf(x2.y); a1[2]=f2bf(x2.z); a1[3]=f2bf(x2.w);
    a1[4]=f2bf(x3.x); a1[5]=f2bf(x3.y); a1[6]=f2bf(x3.z); a1[7]=f2bf(x3.w);
    f32x4 acc[4] = {{0.f,0.f,0.f,0.f},{0.f,0.f,0.f,0.f},{0.f,0.f,0.f,0.f},{0.f,0.f,0.f,0.f}};
#pragma unroll
    for (int t = 0; t < 4; ++t) {
      acc[t] = __builtin_amdgcn_mfma_f32_16x16x32_bf16(a0, bfrag[t][0], acc[t], 0, 0, 0);
      acc[t] = __builtin_amdgcn_mfma_f32_16x16x32_bf16(a1, bfrag[t][1], acc[t], 0, 0, 0);
    }
    const int obase = k * M + mbase + lg * 4;
    int oidx[4];
#pragma unroll
    for (int r = 0; r < 4; ++r) oidx[r] = out_map[obase + r];
#pragma unroll
    for (int t = 0; t < 4; ++t)
#pragma unroll
      for (int r = 0; r < 4; ++r)
        atomicAdd(out + (size_t)oidx[r] * COUT + t * 16 + lr, acc[t][r]);
  }
}

extern "C" void kernel_launch(void* const* d_in, const int* in_sizes, int n_in,
                              void* d_out, int out_size, void* d_ws, size_t ws_size,
                              hipStream_t stream) {
  const float* x = (const float*)d_in[0];
  const float* W = (const float*)d_in[1];
  const int* in_map = (const int*)d_in[2];
  const int* out_map = (const int*)d_in[3];
  float* out = (float*)d_out;
  char* ws = (char*)d_ws;

  const size_t msg_b = (size_t)NMSG * 128;        // 226.5 MB
  const size_t xb_b = (size_t)NVOX * CIN * 2;     // 33.6 MB
  const size_t wf_b = (size_t)KOFF * 4096 * 2;    // 216 KB
  const size_t cnt_b = (size_t)NVOX * 4;          // 1 MB
  auto pad = [](size_t b) { return (b + 255) & ~(size_t)255; };

  size_t need_p1 = pad(msg_b) + pad(wf_b) + 2 * pad(cnt_b) + pad(1024 * 4);
  size_t need_p0 = need_p1 + pad(xb_b);
  bool useXb = (ws_size >= need_p0);

  if (ws_size < need_p1) {
    hipMemsetAsync(d_out, 0, (size_t)out_size * sizeof(float), stream);
    spconv_atomic_kernel<<<dim3(KOFF * TILES_PER_K), dim3(256), 0, stream>>>(
        x, W, in_map, out_map, out);
    return;
  }

  size_t off = 0;
  unsigned short* msg = (unsigned short*)(ws + off); off += pad(msg_b);
  unsigned short* xb = nullptr;
  if (useXb) { xb = (unsigned short*)(ws + off); off += pad(xb_b); }
  unsigned short* Wf = (unsigned short*)(ws + off); off += pad(wf_b);
  int* count  = (int*)(ws + off); off += pad(cnt_b);
  int* cursor = (int*)(ws + off); off += pad(cnt_b);
  int* bsum   = (int*)(ws + off);

  hipMemsetAsync(count, 0, cnt_b, stream);

  int xcvtBlocks = useXb ? XCVT_BLOCKS : 0;
  prep_kernel<<<dim3(xcvtBlocks + COUNT_BLOCKS + KOFF), dim3(256), 0, stream>>>(
      x, W, out_map, xb, Wf, count, xcvtBlocks);

  scan1_kernel<<<dim3(NVOX / 256), dim3(256), 0, stream>>>(count, cursor, bsum);
  scan2_kernel<<<dim3(1), dim3(256), 0, stream>>>(bsum);
  scan3_kernel<<<dim3(NVOX / 256), dim3(256), 0, stream>>>(cursor, bsum);

  if (useXb)
    gemm_msg_kernel<true><<<dim3(KOFF * TILES_PER_K), dim3(256), 0, stream>>>(
        (const void*)xb, Wf, in_map, out_map, cursor, msg);
  else
    gemm_msg_kernel<false><<<dim3(KOFF * TILES_PER_K), dim3(256), 0, stream>>>(
        (const void*)x, Wf, in_map, out_map, cursor, msg);

  gather_out_kernel<<<dim3(NVOX / 32), dim3(256), 0, stream>>>(msg, cursor, count, out);
}

// Round 7
// 257.075 us; speedup vs baseline: 1.4454x; 1.4454x over previous
//
#include <hip/hip_runtime.h>

// Sparse conv, sorted-message pipeline v5.
//   memset count
//   prep (fused): xcvt x->bf16 | histogram out_map | W -> MFMA-fragment layout (Wf)
//   scan1/2/3:    exclusive prefix over count -> cursor (segment starts)
//   gemm:         dist-2 pipelined gather -> bf16 MFMA -> msg row at sorted slot
//                 (slot = atomicAdd(cursor[out]); nontemporal msg stores)
//   gather:       IN-LANE accumulation (zero shuffles): lane=(row,16B-chunk),
//                 8 preloaded independent contributions + masked fma, nt loads.

typedef __attribute__((ext_vector_type(8))) short bf16x8;
typedef __attribute__((ext_vector_type(8))) unsigned short u16x8;
typedef __attribute__((ext_vector_type(4))) unsigned short u16x4;
typedef __attribute__((ext_vector_type(4))) float f32x4;
typedef __attribute__((ext_vector_type(2))) float f32x2;

constexpr int KOFF = 27;
constexpr int M = 65536;
constexpr int CIN = 64;
constexpr int COUT = 64;
constexpr int NVOX = 262144;
constexpr int NMSG = KOFF * M;                 // 1,769,472
constexpr int TM_BLOCK = 512;
constexpr int TILES_PER_K = M / TM_BLOCK;      // 128
constexpr int SUBTILES = TM_BLOCK / (4 * 16);  // 8
constexpr int XCVT_BLOCKS = NVOX * CIN / 8 / 256;  // 8192
constexpr int COUNT_BLOCKS = NMSG / 256;           // 6912

static __device__ __forceinline__ short f2bf(float f) {
  unsigned u = __builtin_bit_cast(unsigned, f);
  unsigned r = (u + 0x7FFFu + ((u >> 16) & 1u)) >> 16;
  return (short)r;
}
static __device__ __forceinline__ float bf2f(unsigned short h) {
  return __builtin_bit_cast(float, (unsigned)h << 16);
}

// ---------------- fused prep: xcvt | count | W-fragment ----------------

__global__ __launch_bounds__(256) void prep_kernel(
    const float* __restrict__ x, const float* __restrict__ W,
    const int* __restrict__ out_map, unsigned short* __restrict__ xb,
    unsigned short* __restrict__ Wf, int* __restrict__ count, int xcvtBlocks) {
  const int b = blockIdx.x;
  if (b < xcvtBlocks) {
    int i = b * 256 + threadIdx.x;
    const float4* p = (const float4*)x + (size_t)i * 2;
    float4 a = p[0], q = p[1];
    u16x8 h;
    h[0] = (unsigned short)f2bf(a.x); h[1] = (unsigned short)f2bf(a.y);
    h[2] = (unsigned short)f2bf(a.z); h[3] = (unsigned short)f2bf(a.w);
    h[4] = (unsigned short)f2bf(q.x); h[5] = (unsigned short)f2bf(q.y);
    h[6] = (unsigned short)f2bf(q.z); h[7] = (unsigned short)f2bf(q.w);
    *(u16x8*)(xb + (size_t)i * 8) = h;
  } else if (b < xcvtBlocks + COUNT_BLOCKS) {
    int i = (b - xcvtBlocks) * 256 + threadIdx.x;
    atomicAdd(&count[out_map[i]], 1);
  } else {
    // W[k] -> fragment order: Wf[k][(t*2+u)*64 + l][j] = W[k][u*32+(l>>4)*8+j][t*16+(l&15)]
    int k = b - xcvtBlocks - COUNT_BLOCKS;  // 0..26
    const float* Wk = W + (size_t)k * (CIN * COUT);
    unsigned short* dst = Wf + (size_t)k * 4096;
#pragma unroll
    for (int i = 0; i < 16; ++i) {
      int e = threadIdx.x * 16 + i;
      int j = e & 7, l = (e >> 3) & 63, tu = e >> 9;
      int t = tu >> 1, u = tu & 1;
      dst[e] = (unsigned short)f2bf(Wk[(u * 32 + (l >> 4) * 8 + j) * COUT + t * 16 + (l & 15)]);
    }
  }
}

// ---------------- scan ----------------

__global__ __launch_bounds__(256) void scan1_kernel(const int* __restrict__ count,
                                                    int* __restrict__ cursor,
                                                    int* __restrict__ blockSums) {
  __shared__ int s[256];
  int t = threadIdx.x, i = blockIdx.x * 256 + t;  // grid = 1024
  int c = count[i];
  s[t] = c; __syncthreads();
  for (int off = 1; off < 256; off <<= 1) {
    int add = (t >= off) ? s[t - off] : 0;
    __syncthreads(); s[t] += add; __syncthreads();
  }
  cursor[i] = s[t] - c;
  if (t == 255) blockSums[blockIdx.x] = s[t];
}

__global__ __launch_bounds__(256) void scan2_kernel(int* __restrict__ bs) {
  __shared__ int s[256];
  int t = threadIdx.x;
  int v0 = bs[t*4], v1 = bs[t*4+1], v2 = bs[t*4+2], v3 = bs[t*4+3];
  int sum = v0 + v1 + v2 + v3;
  s[t] = sum; __syncthreads();
  for (int off = 1; off < 256; off <<= 1) {
    int add = (t >= off) ? s[t - off] : 0;
    __syncthreads(); s[t] += add; __syncthreads();
  }
  int run = s[t] - sum;
  bs[t*4] = run; run += v0;
  bs[t*4+1] = run; run += v1;
  bs[t*4+2] = run; run += v2;
  bs[t*4+3] = run;
}

__global__ __launch_bounds__(256) void scan3_kernel(int* __restrict__ cursor,
                                                    const int* __restrict__ blockBase) {
  int i = blockIdx.x * 256 + threadIdx.x;  // grid = 1024
  cursor[i] += blockBase[blockIdx.x];
}

// ---------------- phase A: pipelined GEMM -> msg at sorted slots ----------------

template <bool BF16IN>
__global__ __launch_bounds__(256) void gemm_msg_kernel(
    const void* __restrict__ xin, const unsigned short* __restrict__ Wf,
    const int* __restrict__ in_map, const int* __restrict__ out_map,
    int* __restrict__ cursor, unsigned short* __restrict__ msg) {
  const int k = blockIdx.x / TILES_PER_K;
  const int mblock = (blockIdx.x % TILES_PER_K) * TM_BLOCK;
  const int wave = threadIdx.x >> 6;
  const int l = threadIdx.x & 63;
  const int lg = l >> 4;
  const int lr = l & 15;

  // B fragments: 8 coalesced 16B loads.
  bf16x8 bfrag[4][2];
  const bf16x8* wf = (const bf16x8*)(Wf + (size_t)k * 4096);
#pragma unroll
  for (int t = 0; t < 4; ++t)
#pragma unroll
    for (int u = 0; u < 2; ++u)
      bfrag[t][u] = wf[(t * 2 + u) * 64 + l];

  const int mwave = mblock + wave * (TM_BLOCK / 4);  // this wave's 128 rows
  const int rb = k * M + mwave;
  int slotA = atomicAdd(&cursor[out_map[rb + l]], 1);       // rows 0..63
  int slotB = atomicAdd(&cursor[out_map[rb + 64 + l]], 1);  // rows 64..127

  auto loadA = [&](int s, bf16x8& A0, bf16x8& A1) {
    int id = in_map[rb + s * 16 + lr];
    if (BF16IN) {
      const unsigned short* xr = (const unsigned short*)xin + (size_t)id * CIN + lg * 8;
      A0 = *(const bf16x8*)(xr);
      A1 = *(const bf16x8*)(xr + 32);
    } else {
      const float* xr = (const float*)xin + (size_t)id * CIN + lg * 8;
      float4 x0 = *(const float4*)(xr);
      float4 x1 = *(const float4*)(xr + 4);
      float4 x2 = *(const float4*)(xr + 32);
      float4 x3 = *(const float4*)(xr + 36);
      A0[0]=f2bf(x0.x); A0[1]=f2bf(x0.y); A0[2]=f2bf(x0.z); A0[3]=f2bf(x0.w);
      A0[4]=f2bf(x1.x); A0[5]=f2bf(x1.y); A0[6]=f2bf(x1.z); A0[7]=f2bf(x1.w);
      A1[0]=f2bf(x2.x); A1[1]=f2bf(x2.y); A1[2]=f2bf(x2.z); A1[3]=f2bf(x2.w);
      A1[4]=f2bf(x3.x); A1[5]=f2bf(x3.y); A1[6]=f2bf(x3.z); A1[7]=f2bf(x3.w);
    }
  };

  bf16x8 c0, c1, n0, n1;
  loadA(0, c0, c1);
  loadA(1, n0, n1);

#pragma unroll 1
  for (int s = 0; s < SUBTILES; ++s) {
    bf16x8 p0, p1;
    const bool have = (s + 2 < SUBTILES);
    if (have) loadA(s + 2, p0, p1);

    f32x4 acc[4] = {{0.f,0.f,0.f,0.f},{0.f,0.f,0.f,0.f},{0.f,0.f,0.f,0.f},{0.f,0.f,0.f,0.f}};
#pragma unroll
    for (int t = 0; t < 4; ++t) {
      acc[t] = __builtin_amdgcn_mfma_f32_16x16x32_bf16(c0, bfrag[t][0], acc[t], 0, 0, 0);
      acc[t] = __builtin_amdgcn_mfma_f32_16x16x32_bf16(c1, bfrag[t][1], acc[t], 0, 0, 0);
    }

    // Row layout: position p = lr*4 + t holds channel t*16 + lr.
    const int slotsrc = (s < 4) ? slotA : slotB;
#pragma unroll
    for (int r = 0; r < 4; ++r) {
      const int sl = __shfl(slotsrc, (s * 16 + lg * 4 + r) & 63, 64);
      u16x4 h;
      h[0] = (unsigned short)f2bf(acc[0][r]);
      h[1] = (unsigned short)f2bf(acc[1][r]);
      h[2] = (unsigned short)f2bf(acc[2][r]);
      h[3] = (unsigned short)f2bf(acc[3][r]);
      // nontemporal: keep L3 for xb; msg is written once, read once.
      __builtin_nontemporal_store(h, (u16x4*)(msg + (size_t)sl * 64 + lr * 4));
    }

    c0 = n0; c1 = n1;
    if (have) { n0 = p0; n1 = p1; }
  }
}

// ---------------- phase B: in-lane contiguous segment sum (no shuffles) --------

__global__ __launch_bounds__(256) void gather_out_kernel(
    const unsigned short* __restrict__ msg, const int* __restrict__ cursorEnd,
    const int* __restrict__ count, float* __restrict__ out) {
  const int wid = (blockIdx.x * 256 + threadIdx.x) >> 6;  // grid = NVOX/32 blocks
  const int p = threadIdx.x & 63;
  const int r = p >> 3;   // which of this wave's 8 output rows
  const int c = p & 7;    // 16B chunk (8 positions) within the 128B msg row
  const int o = wid * 8 + r;

  const int n = count[o];
  const int base = (n > 0) ? (cursorEnd[o] - n) : 0;
  const unsigned short* src = msg + (size_t)base * 64 + c * 8;

  // Preload 8 independent contributions (covers n<=8, ~97.5% of rows).
  u16x8 v[8];
#pragma unroll
  for (int i = 0; i < 8; ++i) {
    int safe = (i < n) ? i : 0;
    v[i] = __builtin_nontemporal_load((const u16x8*)(src + (size_t)safe * 64));
  }
  float acc[8] = {};
#pragma unroll
  for (int i = 0; i < 8; ++i) {
    float m = (i < n) ? 1.0f : 0.0f;
#pragma unroll
    for (int d = 0; d < 8; ++d)
      acc[d] = fmaf(m, bf2f((unsigned short)v[i][d]), acc[d]);
  }
  // Rare tail (n > 8), per-lane.
  for (int i = 8; i < n; ++i) {
    u16x8 t = __builtin_nontemporal_load((const u16x8*)(src + (size_t)i * 64));
#pragma unroll
    for (int d = 0; d < 8; ++d) acc[d] += bf2f((unsigned short)t[d]);
  }

  // position q = c*8 + d -> channel (d&3)*16 + 2c + (d>>2); all 64 lanes store.
  float* orow = out + (size_t)o * 64 + 2 * c;
  f32x2 s0 = {acc[0], acc[4]};
  f32x2 s1 = {acc[1], acc[5]};
  f32x2 s2 = {acc[2], acc[6]};
  f32x2 s3 = {acc[3], acc[7]};
  __builtin_nontemporal_store(s0, (f32x2*)(orow));
  __builtin_nontemporal_store(s1, (f32x2*)(orow + 16));
  __builtin_nontemporal_store(s2, (f32x2*)(orow + 32));
  __builtin_nontemporal_store(s3, (f32x2*)(orow + 48));
}

// ---------------- fallback (atomic scatter) ----------------

__global__ __launch_bounds__(256) void spconv_atomic_kernel(
    const float* __restrict__ x, const float* __restrict__ W,
    const int* __restrict__ in_map, const int* __restrict__ out_map,
    float* __restrict__ out) {
  const int k = blockIdx.x / TILES_PER_K;
  const int mblock = (blockIdx.x % TILES_PER_K) * TM_BLOCK;
  const int wave = threadIdx.x >> 6;
  const int l = threadIdx.x & 63;
  const int lg = l >> 4;
  const int lr = l & 15;
  bf16x8 bfrag[4][2];
  const float* Wk = W + (size_t)k * (CIN * COUT);
#pragma unroll
  for (int t = 0; t < 4; ++t)
#pragma unroll
    for (int u = 0; u < 2; ++u)
#pragma unroll
      for (int j = 0; j < 8; ++j)
        bfrag[t][u][j] = f2bf(Wk[(u * 32 + lg * 8 + j) * COUT + t * 16 + lr]);
  const int mwave = mblock + wave * (TM_BLOCK / 4);
#pragma unroll 1
  for (int s = 0; s < SUBTILES; ++s) {
    const int mbase = mwave + s * 16;
    const int in_idx = in_map[k * M + mbase + lr];
    const float* xr = x + (size_t)in_idx * CIN + lg * 8;
    float4 x0 = *(const float4*)(xr);
    float4 x1 = *(const float4*)(xr + 4);
    float4 x2 = *(const float4*)(xr + 32);
    float4 x3 = *(const float4*)(xr + 36);
    bf16x8 a0, a1;
    a0[0]=f2bf(x0.x); a0[1]=f2bf(x0.y); a0[2]=f2bf(x0.z); a0[3]=f2bf(x0.w);
    a0[4]=f2bf(x1.x); a0[5]=f2bf(x1.y); a0[6]=f2bf(x1.z); a0[7]=f2bf(x1.w);
    a1[0]=f2bf(x2.x); a1[1]=f2bf(x2.y); a1[2]=f2bf(x2.z); a1[3]=f2bf(x2.w);
    a1[4]=f2bf(x3.x); a1[5]=f2bf(x3.y); a1[6]=f2bf(x3.z); a1[7]=f2bf(x3.w);
    f32x4 acc[4] = {{0.f,0.f,0.f,0.f},{0.f,0.f,0.f,0.f},{0.f,0.f,0.f,0.f},{0.f,0.f,0.f,0.f}};
#pragma unroll
    for (int t = 0; t < 4; ++t) {
      acc[t] = __builtin_amdgcn_mfma_f32_16x16x32_bf16(a0, bfrag[t][0], acc[t], 0, 0, 0);
      acc[t] = __builtin_amdgcn_mfma_f32_16x16x32_bf16(a1, bfrag[t][1], acc[t], 0, 0, 0);
    }
    const int obase = k * M + mbase + lg * 4;
    int oidx[4];
#pragma unroll
    for (int r = 0; r < 4; ++r) oidx[r] = out_map[obase + r];
#pragma unroll
    for (int t = 0; t < 4; ++t)
#pragma unroll
      for (int r = 0; r < 4; ++r)
        atomicAdd(out + (size_t)oidx[r] * COUT + t * 16 + lr, acc[t][r]);
  }
}

extern "C" void kernel_launch(void* const* d_in, const int* in_sizes, int n_in,
                              void* d_out, int out_size, void* d_ws, size_t ws_size,
                              hipStream_t stream) {
  const float* x = (const float*)d_in[0];
  const float* W = (const float*)d_in[1];
  const int* in_map = (const int*)d_in[2];
  const int* out_map = (const int*)d_in[3];
  float* out = (float*)d_out;
  char* ws = (char*)d_ws;

  const size_t msg_b = (size_t)NMSG * 128;        // 226.5 MB
  const size_t xb_b = (size_t)NVOX * CIN * 2;     // 33.6 MB
  const size_t wf_b = (size_t)KOFF * 4096 * 2;    // 216 KB
  const size_t cnt_b = (size_t)NVOX * 4;          // 1 MB
  auto pad = [](size_t b) { return (b + 255) & ~(size_t)255; };

  size_t need_p1 = pad(msg_b) + pad(wf_b) + 2 * pad(cnt_b) + pad(1024 * 4);
  size_t need_p0 = need_p1 + pad(xb_b);
  bool useXb = (ws_size >= need_p0);

  if (ws_size < need_p1) {
    hipMemsetAsync(d_out, 0, (size_t)out_size * sizeof(float), stream);
    spconv_atomic_kernel<<<dim3(KOFF * TILES_PER_K), dim3(256), 0, stream>>>(
        x, W, in_map, out_map, out);
    return;
  }

  size_t off = 0;
  unsigned short* msg = (unsigned short*)(ws + off); off += pad(msg_b);
  unsigned short* xb = nullptr;
  if (useXb) { xb = (unsigned short*)(ws + off); off += pad(xb_b); }
  unsigned short* Wf = (unsigned short*)(ws + off); off += pad(wf_b);
  int* count  = (int*)(ws + off); off += pad(cnt_b);
  int* cursor = (int*)(ws + off); off += pad(cnt_b);
  int* bsum   = (int*)(ws + off);

  hipMemsetAsync(count, 0, cnt_b, stream);

  int xcvtBlocks = useXb ? XCVT_BLOCKS : 0;
  prep_kernel<<<dim3(xcvtBlocks + COUNT_BLOCKS + KOFF), dim3(256), 0, stream>>>(
      x, W, out_map, xb, Wf, count, xcvtBlocks);

  scan1_kernel<<<dim3(NVOX / 256), dim3(256), 0, stream>>>(count, cursor, bsum);
  scan2_kernel<<<dim3(1), dim3(256), 0, stream>>>(bsum);
  scan3_kernel<<<dim3(NVOX / 256), dim3(256), 0, stream>>>(cursor, bsum);

  if (useXb)
    gemm_msg_kernel<true><<<dim3(KOFF * TILES_PER_K), dim3(256), 0, stream>>>(
        (const void*)xb, Wf, in_map, out_map, cursor, msg);
  else
    gemm_msg_kernel<false><<<dim3(KOFF * TILES_PER_K), dim3(256), 0, stream>>>(
        (const void*)x, Wf, in_map, out_map, cursor, msg);

  gather_out_kernel<<<dim3(NVOX / 32), dim3(256), 0, stream>>>(msg, cursor, count, out);
}